// Round 1
// baseline (936.141 us; speedup 1.0000x reference)
//
#include <hip/hip_runtime.h>

// Problem constants
#define B 8
#define T 768
#define D 1024
#define H 16
#define DH 64
#define M (B*T)      // 6144
#define N3 (3*D)     // 3072
#define KDIM D       // 1024
#define QKV_ELEMS (B*H*T*DH)  // 6291456 floats per tensor

// ---------------- Kernel 1: RoPE tables ----------------
__global__ void rope_tables_kernel(float* __restrict__ cosT, float* __restrict__ sinT) {
    int idx = blockIdx.x * blockDim.x + threadIdx.x;  // t*32 + i
    if (idx >= T * 32) return;
    int t = idx >> 5;
    int i = idx & 31;
    // inv_freq = 10000^(-(2i)/64), computed in fp32 like the reference
    float inv_freq = powf(10000.0f, -(float)(2 * i) / 64.0f);
    float ang = (float)t * inv_freq;
    cosT[idx] = cosf(ang);
    sinT[idx] = sinf(ang);
}

// ---------------- Kernel 2: QKV GEMM + bias + RoPE + head-layout scatter ----------------
// C[m][n] = sum_k X[m][k] * W[n][k] + bias[n]
// Tile: BM=128 x BN=128, K-tile 16, 256 threads, 8x8 microtile.
// Column mapping per thread: head g = tx>>3, d0 = (tx&7)*4; owns cols {d0..d0+3} and
// {d0+32..d0+35} of head g  -> RoPE pair (d, d+32) lives in the same thread.
#define BM 128
#define BN 128
#define KT 16
#define LDST 132   // padded LDS row stride (floats)

__global__ __launch_bounds__(256) void qkv_gemm_kernel(
    const float* __restrict__ X, const float* __restrict__ W,
    const float* __restrict__ bias, const float* __restrict__ cosT,
    const float* __restrict__ sinT, float* __restrict__ qr,
    float* __restrict__ kr, float* __restrict__ vr)
{
    __shared__ float As[KT][LDST];  // [k][m]
    __shared__ float Bs[KT][LDST];  // [k][n]

    const int tid = threadIdx.x;
    const int tx = tid & 15;        // 0..15
    const int ty = tid >> 4;        // 0..15
    const int g   = tx >> 3;        // head within tile: 0/1
    const int d0  = (tx & 7) << 2;  // 0..28
    const int m0 = blockIdx.x * BM;
    const int n0 = blockIdx.y * BN;

    float acc[8][8];
#pragma unroll
    for (int i = 0; i < 8; ++i)
#pragma unroll
        for (int j = 0; j < 8; ++j) acc[i][j] = 0.0f;

    for (int k0 = 0; k0 < KDIM; k0 += KT) {
        __syncthreads();
        // load A-tile (128x16) and B-tile (128x16), store k-major (transposed)
#pragma unroll
        for (int l = 0; l < 2; ++l) {
            int vid = tid + l * 256;       // 0..511
            int row = vid >> 2;            // 0..127
            int k4  = (vid & 3) << 2;      // 0,4,8,12
            float4 av = *(const float4*)(X + (size_t)(m0 + row) * KDIM + k0 + k4);
            As[k4 + 0][row] = av.x; As[k4 + 1][row] = av.y;
            As[k4 + 2][row] = av.z; As[k4 + 3][row] = av.w;
            float4 bv = *(const float4*)(W + (size_t)(n0 + row) * KDIM + k0 + k4);
            Bs[k4 + 0][row] = bv.x; Bs[k4 + 1][row] = bv.y;
            Bs[k4 + 2][row] = bv.z; Bs[k4 + 3][row] = bv.w;
        }
        __syncthreads();
#pragma unroll
        for (int kk = 0; kk < KT; ++kk) {
            float4 a0 = *(const float4*)&As[kk][ty * 8];
            float4 a1 = *(const float4*)&As[kk][ty * 8 + 4];
            float4 b0 = *(const float4*)&Bs[kk][g * 64 + d0];
            float4 b1 = *(const float4*)&Bs[kk][g * 64 + d0 + 32];
            float a[8], bb[8];
            a[0]=a0.x; a[1]=a0.y; a[2]=a0.z; a[3]=a0.w;
            a[4]=a1.x; a[5]=a1.y; a[6]=a1.z; a[7]=a1.w;
            bb[0]=b0.x; bb[1]=b0.y; bb[2]=b0.z; bb[3]=b0.w;
            bb[4]=b1.x; bb[5]=b1.y; bb[6]=b1.z; bb[7]=b1.w;
#pragma unroll
            for (int i = 0; i < 8; ++i)
#pragma unroll
                for (int j = 0; j < 8; ++j)
                    acc[i][j] = fmaf(a[i], bb[j], acc[i][j]);
        }
    }

    // ---- epilogue: bias (+ RoPE for q,k), scatter to (B,H,T,DH) ----
    const int section = n0 >> 10;            // 0=q,1=k,2=v (uniform per block)
    const int h = ((n0 & 1023) >> 6) + g;    // head index
    float* dst = (section == 0) ? qr : (section == 1) ? kr : vr;

    float bias0[4], bias1[4];
#pragma unroll
    for (int u = 0; u < 4; ++u) {
        bias0[u] = bias[n0 + g * 64 + d0 + u];
        bias1[u] = bias[n0 + g * 64 + d0 + 32 + u];
    }

#pragma unroll
    for (int i = 0; i < 8; ++i) {
        int m = m0 + ty * 8 + i;
        int bidx = m / T;
        int t = m - bidx * T;
        float v0[4], v1[4];
#pragma unroll
        for (int u = 0; u < 4; ++u) {
            v0[u] = acc[i][u]     + bias0[u];
            v1[u] = acc[i][4 + u] + bias1[u];
        }
        if (section < 2) {
            float4 cv = *(const float4*)(cosT + t * 32 + d0);
            float4 sv = *(const float4*)(sinT + t * 32 + d0);
            float c[4], s[4];
            c[0]=cv.x; c[1]=cv.y; c[2]=cv.z; c[3]=cv.w;
            s[0]=sv.x; s[1]=sv.y; s[2]=sv.z; s[3]=sv.w;
#pragma unroll
            for (int u = 0; u < 4; ++u) {
                float lo = v0[u], hi = v1[u];
                v0[u] = lo * c[u] - hi * s[u];   // d < 32: x*cos - x[d+32]*sin
                v1[u] = hi * c[u] + lo * s[u];   // d >=32: x*cos + x[d-32]*sin
            }
        }
        float* rowp = dst + (((size_t)bidx * H + h) * T + t) * DH;
        float4 o0, o1;
        o0.x=v0[0]; o0.y=v0[1]; o0.z=v0[2]; o0.w=v0[3];
        o1.x=v1[0]; o1.y=v1[1]; o1.z=v1[2]; o1.w=v1[3];
        *(float4*)(rowp + d0)      = o0;
        *(float4*)(rowp + d0 + 32) = o1;
    }
}

// ---------------- Kernel 3: causal retention (no softmax) ----------------
// block = (q-tile of 64 rows, one (b,h)); iterate s-tiles <= q-tile.
__global__ __launch_bounds__(256) void retention_kernel(
    const float* __restrict__ qr, const float* __restrict__ kr,
    const float* __restrict__ vr, float* __restrict__ out)
{
    __shared__ float Qs[64][68];    // [r][d]
    __shared__ float KsT[64][68];   // [d][c]  (transposed)
    __shared__ float Vs[64][68];    // [j][d]
    __shared__ float Ss[64][68];    // [r][c]

    const int qt = blockIdx.x;      // 0..11
    const int bh = blockIdx.y;      // 0..127
    const int b = bh >> 4;
    const int h = bh & 15;
    const int tid = threadIdx.x;
    const int tx = tid & 15;
    const int ty = tid >> 4;

    const float* qbase = qr + ((size_t)bh * T + qt * 64) * DH;
#pragma unroll
    for (int l = 0; l < 4; ++l) {
        int vid = tid + l * 256;        // 0..1023
        int row = vid >> 4;             // 0..63
        int c4  = (vid & 15) << 2;      // 0..60
        *(float4*)&Qs[row][c4] = *(const float4*)(qbase + row * DH + c4);
    }

    float acc[4][4];
#pragma unroll
    for (int a = 0; a < 4; ++a)
#pragma unroll
        for (int c = 0; c < 4; ++c) acc[a][c] = 0.0f;

    for (int st = 0; st <= qt; ++st) {
        __syncthreads();   // protects Qs (first iter) and KsT/Vs/Ss reuse
        const float* kb = kr + ((size_t)bh * T + st * 64) * DH;
        const float* vb = vr + ((size_t)bh * T + st * 64) * DH;
#pragma unroll
        for (int l = 0; l < 4; ++l) {
            int vid = tid + l * 256;
            int row = vid >> 4;
            int c4  = (vid & 15) << 2;
            float4 kv = *(const float4*)(kb + row * DH + c4);
            KsT[c4 + 0][row] = kv.x; KsT[c4 + 1][row] = kv.y;
            KsT[c4 + 2][row] = kv.z; KsT[c4 + 3][row] = kv.w;
            *(float4*)&Vs[row][c4] = *(const float4*)(vb + row * DH + c4);
        }
        __syncthreads();

        // S = Q K^T  (64x64), thread owns rows ty*4.., cols tx*4..
        float sacc[4][4];
#pragma unroll
        for (int a = 0; a < 4; ++a)
#pragma unroll
            for (int c = 0; c < 4; ++c) sacc[a][c] = 0.0f;

#pragma unroll
        for (int d = 0; d < 64; d += 4) {
            float q[4][4], kv[4][4];
#pragma unroll
            for (int a = 0; a < 4; ++a) {
                float4 qv = *(const float4*)&Qs[ty * 4 + a][d];
                q[a][0]=qv.x; q[a][1]=qv.y; q[a][2]=qv.z; q[a][3]=qv.w;
            }
#pragma unroll
            for (int dd = 0; dd < 4; ++dd) {
                float4 kvv = *(const float4*)&KsT[d + dd][tx * 4];
                kv[dd][0]=kvv.x; kv[dd][1]=kvv.y; kv[dd][2]=kvv.z; kv[dd][3]=kvv.w;
            }
#pragma unroll
            for (int a = 0; a < 4; ++a)
#pragma unroll
                for (int dd = 0; dd < 4; ++dd)
#pragma unroll
                    for (int c = 0; c < 4; ++c)
                        sacc[a][c] = fmaf(q[a][dd], kv[dd][c], sacc[a][c]);
        }

        const bool diag = (st == qt);
#pragma unroll
        for (int a = 0; a < 4; ++a) {
            int r = ty * 4 + a;
            float4 sv;
            sv.x = sacc[a][0]; sv.y = sacc[a][1]; sv.z = sacc[a][2]; sv.w = sacc[a][3];
            if (diag) {
                int c0 = tx * 4;
                if (c0 + 0 > r) sv.x = 0.0f;
                if (c0 + 1 > r) sv.y = 0.0f;
                if (c0 + 2 > r) sv.z = 0.0f;
                if (c0 + 3 > r) sv.w = 0.0f;
            }
            *(float4*)&Ss[r][tx * 4] = sv;
        }
        __syncthreads();

        // O += S @ V
#pragma unroll
        for (int j = 0; j < 64; j += 4) {
            float srow[4][4], vrow[4][4];
#pragma unroll
            for (int a = 0; a < 4; ++a) {
                float4 s4 = *(const float4*)&Ss[ty * 4 + a][j];
                srow[a][0]=s4.x; srow[a][1]=s4.y; srow[a][2]=s4.z; srow[a][3]=s4.w;
            }
#pragma unroll
            for (int jj = 0; jj < 4; ++jj) {
                float4 v4 = *(const float4*)&Vs[j + jj][tx * 4];
                vrow[jj][0]=v4.x; vrow[jj][1]=v4.y; vrow[jj][2]=v4.z; vrow[jj][3]=v4.w;
            }
#pragma unroll
            for (int a = 0; a < 4; ++a)
#pragma unroll
                for (int jj = 0; jj < 4; ++jj)
#pragma unroll
                    for (int c = 0; c < 4; ++c)
                        acc[a][c] = fmaf(srow[a][jj], vrow[jj][c], acc[a][c]);
        }
    }

    // write O tile: out[b][t][h*64 + dcol]
#pragma unroll
    for (int a = 0; a < 4; ++a) {
        int t = qt * 64 + ty * 4 + a;
        float4 o;
        o.x = acc[a][0]; o.y = acc[a][1]; o.z = acc[a][2]; o.w = acc[a][3];
        *(float4*)(out + ((size_t)b * T + t) * D + h * DH + tx * 4) = o;
    }
}

// ---------------- launch ----------------
extern "C" void kernel_launch(void* const* d_in, const int* in_sizes, int n_in,
                              void* d_out, int out_size, void* d_ws, size_t ws_size,
                              hipStream_t stream) {
    const float* x    = (const float*)d_in[0];
    const float* Wq   = (const float*)d_in[1];
    const float* bq   = (const float*)d_in[2];
    float* out = (float*)d_out;
    float* ws  = (float*)d_ws;

    float* qr   = ws;                       // 6.29M floats
    float* kr   = ws + (size_t)QKV_ELEMS;
    float* vr   = ws + (size_t)2 * QKV_ELEMS;
    float* cosT = ws + (size_t)3 * QKV_ELEMS;
    float* sinT = cosT + T * 32;

    rope_tables_kernel<<<dim3((T * 32 + 255) / 256), dim3(256), 0, stream>>>(cosT, sinT);
    qkv_gemm_kernel<<<dim3(M / BM, N3 / BN), dim3(256), 0, stream>>>(
        x, Wq, bq, cosT, sinT, qr, kr, vr);
    retention_kernel<<<dim3(T / 64, B * H), dim3(256), 0, stream>>>(qr, kr, vr, out);
}

// Round 3
// 625.651 us; speedup vs baseline: 1.4963x; 1.4963x over previous
//
#include <hip/hip_runtime.h>

// Problem constants
#define B 8
#define T 768
#define D 1024
#define H 16
#define DH 64
#define M (B*T)      // 6144
#define N3 (3*D)     // 3072
#define KDIM D       // 1024
#define QKV_ELEMS (B*H*T*DH)  // 6291456 floats per tensor

typedef __attribute__((ext_vector_type(8))) short bf16x8;
typedef __attribute__((ext_vector_type(4))) float f32x4;

__device__ __forceinline__ unsigned short f2bf(float x) {
    union { float f; unsigned u; } a; a.f = x;
    unsigned r = a.u + 0x7FFFu + ((a.u >> 16) & 1u);
    return (unsigned short)(r >> 16);
}
__device__ __forceinline__ float bf2f(unsigned short h) {
    union { unsigned u; float f; } a; a.u = ((unsigned)h) << 16;
    return a.f;
}

// ---------------- Kernel 1: RoPE tables ----------------
__global__ void rope_tables_kernel(float* __restrict__ cosT, float* __restrict__ sinT) {
    int idx = blockIdx.x * blockDim.x + threadIdx.x;  // t*32 + i
    if (idx >= T * 32) return;
    int t = idx >> 5;
    int i = idx & 31;
    float inv_freq = powf(10000.0f, -(float)(2 * i) / 64.0f);
    float ang = (float)t * inv_freq;
    cosT[idx] = cosf(ang);
    sinT[idx] = sinf(ang);
}

// ---------------- Kernel 2: QKV GEMM via bf16 split-3 MFMA ----------------
// C[m][n] = sum_k X[m][k]*W[n][k] + bias[n], then RoPE (q,k sections) + scatter.
// Tile 128x128, BK=32, 256 threads = 4 waves in 2x2; each wave 64x64 via 4x4
// fragments of mfma_f32_16x16x32_bf16.
// Split-3: x = hi + lo (bf16 each); product = hi*hi + hi*lo + lo*hi (fp32 acc).
// LDS layout: [row][32 k] bf16, 4 chunks of 8 bf16 per row, chunk XOR-swizzled
// with (row>>1)&3 so ds_write_b128/ds_read_b128 are conflict-minimal.
#define BMq 128
#define BNq 128
#define BKq 32

__global__ __launch_bounds__(256) void qkv_mfma_kernel(
    const float* __restrict__ X, const float* __restrict__ W,
    const float* __restrict__ bias, const float* __restrict__ cosT,
    const float* __restrict__ sinT, float* __restrict__ qr,
    float* __restrict__ kr, float* __restrict__ vr)
{
    __shared__ unsigned short Ahi[BMq * BKq];
    __shared__ unsigned short Alo[BMq * BKq];
    __shared__ unsigned short Bhi[BNq * BKq];
    __shared__ unsigned short Blo[BNq * BKq];

    const int tid  = threadIdx.x;
    const int lane = tid & 63;
    const int w    = tid >> 6;      // wave 0..3
    const int wr   = w >> 1;        // wave row 0..1
    const int wc   = w & 1;         // wave col 0..1
    const int lr   = lane & 15;     // fragment row/col lane
    const int kc   = lane >> 4;     // k-chunk 0..3

    const int m0 = blockIdx.x * BMq;
    const int n0 = blockIdx.y * BNq;

    // staging coords: each thread owns half a row (16 k-elems)
    const int srow = tid >> 1;
    const int kh   = tid & 1;

    f32x4 acc[4][4];
#pragma unroll
    for (int m = 0; m < 4; ++m)
#pragma unroll
        for (int n = 0; n < 4; ++n) acc[m][n] = (f32x4){0.f, 0.f, 0.f, 0.f};

    for (int k0 = 0; k0 < KDIM; k0 += BKq) {
        __syncthreads();
        // ---- stage A (X) and B (W) tiles, fp32 -> bf16 hi/lo ----
        {
            const float* src = X + (size_t)(m0 + srow) * KDIM + k0 + kh * 16;
            float v[16];
#pragma unroll
            for (int i = 0; i < 4; ++i) ((float4*)v)[i] = ((const float4*)src)[i];
#pragma unroll
            for (int c = 0; c < 2; ++c) {
                int chunk = kh * 2 + c;
                int sidx = srow * 32 + ((chunk ^ ((srow >> 1) & 3)) * 8);
                union { unsigned short u[8]; bf16x8 v8; } hiu, lou;
#pragma unroll
                for (int e = 0; e < 8; ++e) {
                    float x = v[c * 8 + e];
                    unsigned short h = f2bf(x);
                    hiu.u[e] = h;
                    lou.u[e] = f2bf(x - bf2f(h));
                }
                *(bf16x8*)&Ahi[sidx] = hiu.v8;
                *(bf16x8*)&Alo[sidx] = lou.v8;
            }
        }
        {
            const float* src = W + (size_t)(n0 + srow) * KDIM + k0 + kh * 16;
            float v[16];
#pragma unroll
            for (int i = 0; i < 4; ++i) ((float4*)v)[i] = ((const float4*)src)[i];
#pragma unroll
            for (int c = 0; c < 2; ++c) {
                int chunk = kh * 2 + c;
                int sidx = srow * 32 + ((chunk ^ ((srow >> 1) & 3)) * 8);
                union { unsigned short u[8]; bf16x8 v8; } hiu, lou;
#pragma unroll
                for (int e = 0; e < 8; ++e) {
                    float x = v[c * 8 + e];
                    unsigned short h = f2bf(x);
                    hiu.u[e] = h;
                    lou.u[e] = f2bf(x - bf2f(h));
                }
                *(bf16x8*)&Bhi[sidx] = hiu.v8;
                *(bf16x8*)&Blo[sidx] = lou.v8;
            }
        }
        __syncthreads();

        // ---- fragment loads ----
        bf16x8 ah[4], al[4], bh[4], bl[4];
#pragma unroll
        for (int m = 0; m < 4; ++m) {
            int row = wr * 64 + m * 16 + lr;
            int idx = row * 32 + ((kc ^ ((row >> 1) & 3)) * 8);
            ah[m] = *(const bf16x8*)&Ahi[idx];
            al[m] = *(const bf16x8*)&Alo[idx];
        }
#pragma unroll
        for (int n = 0; n < 4; ++n) {
            int col = wc * 64 + n * 16 + lr;
            int idx = col * 32 + ((kc ^ ((col >> 1) & 3)) * 8);
            bh[n] = *(const bf16x8*)&Bhi[idx];
            bl[n] = *(const bf16x8*)&Blo[idx];
        }

        // ---- MFMA: hi*hi + hi*lo + lo*hi ----
#pragma unroll
        for (int m = 0; m < 4; ++m)
#pragma unroll
            for (int n = 0; n < 4; ++n) {
                acc[m][n] = __builtin_amdgcn_mfma_f32_16x16x32_bf16(ah[m], bh[n], acc[m][n], 0, 0, 0);
                acc[m][n] = __builtin_amdgcn_mfma_f32_16x16x32_bf16(ah[m], bl[n], acc[m][n], 0, 0, 0);
                acc[m][n] = __builtin_amdgcn_mfma_f32_16x16x32_bf16(al[m], bh[n], acc[m][n], 0, 0, 0);
            }
    }

    // ---- epilogue: bias + RoPE + scatter to (B,H,T,DH) ----
    // C/D layout: col = lane&15, row = (lane>>4)*4 + reg  [m89-verified]
    const int section = n0 >> 10;                       // 0=q,1=k,2=v
    float* dst = (section == 0) ? qr : (section == 1) ? kr : vr;
    const int hcol = ((n0 & 1023) >> 6) + wc;           // head index

    float biasv[2][2];
#pragma unroll
    for (int np = 0; np < 2; ++np) {
        biasv[np][0] = bias[n0 + wc * 64 + np * 16 + lr];
        biasv[np][1] = bias[n0 + wc * 64 + np * 16 + lr + 32];
    }

#pragma unroll
    for (int m = 0; m < 4; ++m) {
#pragma unroll
        for (int j = 0; j < 4; ++j) {
            int grow = m0 + wr * 64 + m * 16 + (lane >> 4) * 4 + j;
            int bidx = grow / T;
            int t = grow - bidx * T;
            float* rowp = dst + (((size_t)bidx * H + hcol) * T + t) * DH;
#pragma unroll
            for (int np = 0; np < 2; ++np) {
                int d = np * 16 + lr;                   // 0..31
                float vlo = acc[m][np][j]     + biasv[np][0];
                float vhi = acc[m][np + 2][j] + biasv[np][1];
                if (section < 2) {
                    float c = cosT[t * 32 + d];
                    float s = sinT[t * 32 + d];
                    float nl = vlo * c - vhi * s;
                    float nh = vhi * c + vlo * s;
                    vlo = nl; vhi = nh;
                }
                rowp[d]      = vlo;
                rowp[d + 32] = vhi;
            }
        }
    }
}

// ---------------- Kernel 3: causal retention (no softmax), fp32 (unchanged) ----------------
__global__ __launch_bounds__(256) void retention_kernel(
    const float* __restrict__ qr, const float* __restrict__ kr,
    const float* __restrict__ vr, float* __restrict__ out)
{
    __shared__ float Qs[64][68];
    __shared__ float KsT[64][68];
    __shared__ float Vs[64][68];
    __shared__ float Ss[64][68];

    const int qt = blockIdx.x;
    const int bh = blockIdx.y;
    const int b = bh >> 4;
    const int h = bh & 15;
    const int tid = threadIdx.x;
    const int tx = tid & 15;
    const int ty = tid >> 4;

    const float* qbase = qr + ((size_t)bh * T + qt * 64) * DH;
#pragma unroll
    for (int l = 0; l < 4; ++l) {
        int vid = tid + l * 256;
        int row = vid >> 4;
        int c4  = (vid & 15) << 2;
        *(float4*)&Qs[row][c4] = *(const float4*)(qbase + row * DH + c4);
    }

    float acc[4][4];
#pragma unroll
    for (int a = 0; a < 4; ++a)
#pragma unroll
        for (int c = 0; c < 4; ++c) acc[a][c] = 0.0f;

    for (int st = 0; st <= qt; ++st) {
        __syncthreads();
        const float* kb = kr + ((size_t)bh * T + st * 64) * DH;
        const float* vb = vr + ((size_t)bh * T + st * 64) * DH;
#pragma unroll
        for (int l = 0; l < 4; ++l) {
            int vid = tid + l * 256;
            int row = vid >> 4;
            int c4  = (vid & 15) << 2;
            float4 kv = *(const float4*)(kb + row * DH + c4);
            KsT[c4 + 0][row] = kv.x; KsT[c4 + 1][row] = kv.y;
            KsT[c4 + 2][row] = kv.z; KsT[c4 + 3][row] = kv.w;
            *(float4*)&Vs[row][c4] = *(const float4*)(vb + row * DH + c4);
        }
        __syncthreads();

        float sacc[4][4];
#pragma unroll
        for (int a = 0; a < 4; ++a)
#pragma unroll
            for (int c = 0; c < 4; ++c) sacc[a][c] = 0.0f;

#pragma unroll
        for (int d = 0; d < 64; d += 4) {
            float q[4][4], kv[4][4];
#pragma unroll
            for (int a = 0; a < 4; ++a) {
                float4 qv = *(const float4*)&Qs[ty * 4 + a][d];
                q[a][0]=qv.x; q[a][1]=qv.y; q[a][2]=qv.z; q[a][3]=qv.w;
            }
#pragma unroll
            for (int dd = 0; dd < 4; ++dd) {
                float4 kvv = *(const float4*)&KsT[d + dd][tx * 4];
                kv[dd][0]=kvv.x; kv[dd][1]=kvv.y; kv[dd][2]=kvv.z; kv[dd][3]=kvv.w;
            }
#pragma unroll
            for (int a = 0; a < 4; ++a)
#pragma unroll
                for (int dd = 0; dd < 4; ++dd)
#pragma unroll
                    for (int c = 0; c < 4; ++c)
                        sacc[a][c] = fmaf(q[a][dd], kv[dd][c], sacc[a][c]);
        }

        const bool diag = (st == qt);
#pragma unroll
        for (int a = 0; a < 4; ++a) {
            int r = ty * 4 + a;
            float4 sv;
            sv.x = sacc[a][0]; sv.y = sacc[a][1]; sv.z = sacc[a][2]; sv.w = sacc[a][3];
            if (diag) {
                int c0 = tx * 4;
                if (c0 + 0 > r) sv.x = 0.0f;
                if (c0 + 1 > r) sv.y = 0.0f;
                if (c0 + 2 > r) sv.z = 0.0f;
                if (c0 + 3 > r) sv.w = 0.0f;
            }
            *(float4*)&Ss[r][tx * 4] = sv;
        }
        __syncthreads();

#pragma unroll
        for (int j = 0; j < 64; j += 4) {
            float srow[4][4], vrow[4][4];
#pragma unroll
            for (int a = 0; a < 4; ++a) {
                float4 s4 = *(const float4*)&Ss[ty * 4 + a][j];
                srow[a][0]=s4.x; srow[a][1]=s4.y; srow[a][2]=s4.z; srow[a][3]=s4.w;
            }
#pragma unroll
            for (int jj = 0; jj < 4; ++jj) {
                float4 v4 = *(const float4*)&Vs[j + jj][tx * 4];
                vrow[jj][0]=v4.x; vrow[jj][1]=v4.y; vrow[jj][2]=v4.z; vrow[jj][3]=v4.w;
            }
#pragma unroll
            for (int a = 0; a < 4; ++a)
#pragma unroll
                for (int jj = 0; jj < 4; ++jj)
#pragma unroll
                    for (int c = 0; c < 4; ++c)
                        acc[a][c] = fmaf(srow[a][jj], vrow[jj][c], acc[a][c]);
        }
    }

#pragma unroll
    for (int a = 0; a < 4; ++a) {
        int t = qt * 64 + ty * 4 + a;
        float4 o;
        o.x = acc[a][0]; o.y = acc[a][1]; o.z = acc[a][2]; o.w = acc[a][3];
        *(float4*)(out + ((size_t)b * T + t) * D + h * DH + tx * 4) = o;
    }
}

// ---------------- launch ----------------
extern "C" void kernel_launch(void* const* d_in, const int* in_sizes, int n_in,
                              void* d_out, int out_size, void* d_ws, size_t ws_size,
                              hipStream_t stream) {
    const float* x    = (const float*)d_in[0];
    const float* Wq   = (const float*)d_in[1];
    const float* bq   = (const float*)d_in[2];
    float* out = (float*)d_out;
    float* ws  = (float*)d_ws;

    float* qr   = ws;
    float* kr   = ws + (size_t)QKV_ELEMS;
    float* vr   = ws + (size_t)2 * QKV_ELEMS;
    float* cosT = ws + (size_t)3 * QKV_ELEMS;
    float* sinT = cosT + T * 32;

    rope_tables_kernel<<<dim3((T * 32 + 255) / 256), dim3(256), 0, stream>>>(cosT, sinT);
    qkv_mfma_kernel<<<dim3(M / BMq, N3 / BNq), dim3(256), 0, stream>>>(
        x, Wq, bq, cosT, sinT, qr, kr, vr);
    retention_kernel<<<dim3(T / 64, B * H), dim3(256), 0, stream>>>(qr, kr, vr, out);
}

// Round 5
// 374.036 us; speedup vs baseline: 2.5028x; 1.6727x over previous
//
#include <hip/hip_runtime.h>

// Problem constants
#define B 8
#define T 768
#define D 1024
#define H 16
#define DH 64
#define M (B*T)      // 6144
#define N3 (3*D)     // 3072
#define KDIM D       // 1024
#define QKV_ELEMS (B*H*T*DH)  // 6291456 floats per tensor

typedef __attribute__((ext_vector_type(8))) short bf16x8;
typedef __attribute__((ext_vector_type(4))) short bf16x4;
typedef __attribute__((ext_vector_type(4))) float f32x4;

__device__ __forceinline__ unsigned short f2bf(float x) {
    union { float f; unsigned u; } a; a.f = x;
    unsigned r = a.u + 0x7FFFu + ((a.u >> 16) & 1u);
    return (unsigned short)(r >> 16);
}
__device__ __forceinline__ float bf2f(unsigned short h) {
    union { unsigned u; float f; } a; a.u = ((unsigned)h) << 16;
    return a.f;
}

// ---------------- Kernel 1: RoPE tables ----------------
__global__ void rope_tables_kernel(float* __restrict__ cosT, float* __restrict__ sinT) {
    int idx = blockIdx.x * blockDim.x + threadIdx.x;  // t*32 + i
    if (idx >= T * 32) return;
    int t = idx >> 5;
    int i = idx & 31;
    float inv_freq = powf(10000.0f, -(float)(2 * i) / 64.0f);
    float ang = (float)t * inv_freq;
    cosT[idx] = cosf(ang);
    sinT[idx] = sinf(ang);
}

// ---------------- Kernel 2: QKV GEMM via bf16 split-3 MFMA (verified r3) ----------------
#define BMq 128
#define BNq 128
#define BKq 32

__global__ __launch_bounds__(256) void qkv_mfma_kernel(
    const float* __restrict__ X, const float* __restrict__ W,
    const float* __restrict__ bias, const float* __restrict__ cosT,
    const float* __restrict__ sinT, float* __restrict__ qr,
    float* __restrict__ kr, float* __restrict__ vr)
{
    __shared__ unsigned short Ahi[BMq * BKq];
    __shared__ unsigned short Alo[BMq * BKq];
    __shared__ unsigned short Bhi[BNq * BKq];
    __shared__ unsigned short Blo[BNq * BKq];

    const int tid  = threadIdx.x;
    const int lane = tid & 63;
    const int w    = tid >> 6;      // wave 0..3
    const int wr   = w >> 1;        // wave row 0..1
    const int wc   = w & 1;         // wave col 0..1
    const int lr   = lane & 15;     // fragment row/col lane
    const int kc   = lane >> 4;     // k-chunk 0..3

    const int m0 = blockIdx.x * BMq;
    const int n0 = blockIdx.y * BNq;

    const int srow = tid >> 1;
    const int kh   = tid & 1;

    f32x4 acc[4][4];
#pragma unroll
    for (int m = 0; m < 4; ++m)
#pragma unroll
        for (int n = 0; n < 4; ++n) acc[m][n] = (f32x4){0.f, 0.f, 0.f, 0.f};

    for (int k0 = 0; k0 < KDIM; k0 += BKq) {
        __syncthreads();
        {
            const float* src = X + (size_t)(m0 + srow) * KDIM + k0 + kh * 16;
            float v[16];
#pragma unroll
            for (int i = 0; i < 4; ++i) ((float4*)v)[i] = ((const float4*)src)[i];
#pragma unroll
            for (int c = 0; c < 2; ++c) {
                int chunk = kh * 2 + c;
                int sidx = srow * 32 + ((chunk ^ ((srow >> 1) & 3)) * 8);
                union { unsigned short u[8]; bf16x8 v8; } hiu, lou;
#pragma unroll
                for (int e = 0; e < 8; ++e) {
                    float x = v[c * 8 + e];
                    unsigned short h = f2bf(x);
                    hiu.u[e] = h;
                    lou.u[e] = f2bf(x - bf2f(h));
                }
                *(bf16x8*)&Ahi[sidx] = hiu.v8;
                *(bf16x8*)&Alo[sidx] = lou.v8;
            }
        }
        {
            const float* src = W + (size_t)(n0 + srow) * KDIM + k0 + kh * 16;
            float v[16];
#pragma unroll
            for (int i = 0; i < 4; ++i) ((float4*)v)[i] = ((const float4*)src)[i];
#pragma unroll
            for (int c = 0; c < 2; ++c) {
                int chunk = kh * 2 + c;
                int sidx = srow * 32 + ((chunk ^ ((srow >> 1) & 3)) * 8);
                union { unsigned short u[8]; bf16x8 v8; } hiu, lou;
#pragma unroll
                for (int e = 0; e < 8; ++e) {
                    float x = v[c * 8 + e];
                    unsigned short h = f2bf(x);
                    hiu.u[e] = h;
                    lou.u[e] = f2bf(x - bf2f(h));
                }
                *(bf16x8*)&Bhi[sidx] = hiu.v8;
                *(bf16x8*)&Blo[sidx] = lou.v8;
            }
        }
        __syncthreads();

        bf16x8 ah[4], al[4], bh[4], bl[4];
#pragma unroll
        for (int m = 0; m < 4; ++m) {
            int row = wr * 64 + m * 16 + lr;
            int idx = row * 32 + ((kc ^ ((row >> 1) & 3)) * 8);
            ah[m] = *(const bf16x8*)&Ahi[idx];
            al[m] = *(const bf16x8*)&Alo[idx];
        }
#pragma unroll
        for (int n = 0; n < 4; ++n) {
            int col = wc * 64 + n * 16 + lr;
            int idx = col * 32 + ((kc ^ ((col >> 1) & 3)) * 8);
            bh[n] = *(const bf16x8*)&Bhi[idx];
            bl[n] = *(const bf16x8*)&Blo[idx];
        }

#pragma unroll
        for (int m = 0; m < 4; ++m)
#pragma unroll
            for (int n = 0; n < 4; ++n) {
                acc[m][n] = __builtin_amdgcn_mfma_f32_16x16x32_bf16(ah[m], bh[n], acc[m][n], 0, 0, 0);
                acc[m][n] = __builtin_amdgcn_mfma_f32_16x16x32_bf16(ah[m], bl[n], acc[m][n], 0, 0, 0);
                acc[m][n] = __builtin_amdgcn_mfma_f32_16x16x32_bf16(al[m], bh[n], acc[m][n], 0, 0, 0);
            }
    }

    const int section = n0 >> 10;                       // 0=q,1=k,2=v
    float* dst = (section == 0) ? qr : (section == 1) ? kr : vr;
    const int hcol = ((n0 & 1023) >> 6) + wc;           // head index

    float biasv[2][2];
#pragma unroll
    for (int np = 0; np < 2; ++np) {
        biasv[np][0] = bias[n0 + wc * 64 + np * 16 + lr];
        biasv[np][1] = bias[n0 + wc * 64 + np * 16 + lr + 32];
    }

#pragma unroll
    for (int m = 0; m < 4; ++m) {
#pragma unroll
        for (int j = 0; j < 4; ++j) {
            int grow = m0 + wr * 64 + m * 16 + (lane >> 4) * 4 + j;
            int bidx = grow / T;
            int t = grow - bidx * T;
            float* rowp = dst + (((size_t)bidx * H + hcol) * T + t) * DH;
#pragma unroll
            for (int np = 0; np < 2; ++np) {
                int d = np * 16 + lr;                   // 0..31
                float vlo = acc[m][np][j]     + biasv[np][0];
                float vhi = acc[m][np + 2][j] + biasv[np][1];
                if (section < 2) {
                    float c = cosT[t * 32 + d];
                    float s = sinT[t * 32 + d];
                    float nl = vlo * c - vhi * s;
                    float nh = vhi * c + vlo * s;
                    vlo = nl; vhi = nh;
                }
                rowp[d]      = vlo;
                rowp[d + 32] = vhi;
            }
        }
    }
}

// ---------------- Kernel 3: retention via bf16 split-3 MFMA ----------------
// Block = 128 q-rows of one (b,h); 4 waves in 2x2 (wm: q-half, wc: col-half).
// Per 64-wide s-tile: QK^T (Q frags in regs, K in LDS) -> mask -> S hi/lo to
// LDS (layout conversion C/D -> A-operand) -> PV with V transposed in LDS.
// All LDS tiles use stride LDK=72 elems (144B: 16B-aligned, row hits bank bits
// -> reads 2-way/free; no XOR swizzle needed).
#define SBLK 64
#define QBLK 128
#define LDK 72

__global__ __launch_bounds__(256) void retention_mfma_kernel(
    const float* __restrict__ qr, const float* __restrict__ kr,
    const float* __restrict__ vr, float* __restrict__ out)
{
    __shared__ unsigned short Khi[SBLK * LDK], Klo[SBLK * LDK];   // [s][d]
    __shared__ unsigned short Vthi[DH * LDK], Vtlo[DH * LDK];     // [d][s] (transposed)
    __shared__ unsigned short Shi[QBLK * LDK], Slo[QBLK * LDK];   // [r][s]

    const int qb = blockIdx.x;       // 0..5
    const int bh = blockIdx.y;       // 0..127
    const int b = bh >> 4, h = bh & 15;
    const int tid = threadIdx.x;
    const int lane = tid & 63;
    const int w = tid >> 6;
    const int wm = w >> 1;           // q-half 0..1
    const int wc = w & 1;            // col-half 0..1
    const int lr = lane & 15;
    const int lg = lane >> 4;        // 0..3

    // ---- Q fragments in registers (hi/lo), loaded once ----
    // A-frag: row = lane&15, k = (lane>>4)*8 + e  [verified r3]
    bf16x8 qh[4][2], ql[4][2];
    {
        const float* qp = qr + ((size_t)bh * T + (size_t)qb * QBLK + wm * 64) * DH;
#pragma unroll
        for (int m = 0; m < 4; ++m)
#pragma unroll
            for (int kk = 0; kk < 2; ++kk) {
                const float* p = qp + (m * 16 + lr) * DH + kk * 32 + lg * 8;
                float v[8];
                *(float4*)&v[0] = *(const float4*)p;
                *(float4*)&v[4] = *(const float4*)(p + 4);
                union { unsigned short u[8]; bf16x8 v8; } hu, lu;
#pragma unroll
                for (int e = 0; e < 8; ++e) {
                    unsigned short hv = f2bf(v[e]);
                    hu.u[e] = hv;
                    lu.u[e] = f2bf(v[e] - bf2f(hv));
                }
                qh[m][kk] = hu.v8;
                ql[m][kk] = lu.v8;
            }
    }

    f32x4 oacc[4][2];
#pragma unroll
    for (int m = 0; m < 4; ++m)
#pragma unroll
        for (int n = 0; n < 2; ++n) oacc[m][n] = (f32x4){0.f, 0.f, 0.f, 0.f};

    const int qmin = qb * QBLK + wm * 64;   // first q-row this wave owns
    const int niter = 2 * qb + 2;

    for (int sb = 0; sb < niter; ++sb) {
        __syncthreads();
        // ---- stage K [s][d] ----
        {
            int row = tid >> 2, d0 = (tid & 3) * 16;
            const float* src = kr + ((size_t)bh * T + (size_t)sb * SBLK + row) * DH + d0;
            float v[16];
#pragma unroll
            for (int i = 0; i < 4; ++i) *(float4*)&v[i * 4] = *(const float4*)(src + i * 4);
#pragma unroll
            for (int c = 0; c < 2; ++c) {
                union { unsigned short u[8]; bf16x8 v8; } hu, lu;
#pragma unroll
                for (int e = 0; e < 8; ++e) {
                    float x = v[c * 8 + e];
                    unsigned short hv = f2bf(x);
                    hu.u[e] = hv;
                    lu.u[e] = f2bf(x - bf2f(hv));
                }
                int idx = row * LDK + d0 + c * 8;
                *(bf16x8*)&Khi[idx] = hu.v8;
                *(bf16x8*)&Klo[idx] = lu.v8;
            }
        }
        // ---- stage V transposed [d][s] ----
        {
            int s0 = (tid >> 4) * 4, d0 = (tid & 15) * 4;
            const float* src = vr + ((size_t)bh * T + (size_t)sb * SBLK + s0) * DH + d0;
            float rv[4][4];
#pragma unroll
            for (int i = 0; i < 4; ++i) *(float4*)&rv[i][0] = *(const float4*)(src + (size_t)i * DH);
#pragma unroll
            for (int j = 0; j < 4; ++j) {
                union { unsigned short u[4]; bf16x4 v4; } hu, lu;
#pragma unroll
                for (int i = 0; i < 4; ++i) {
                    float x = rv[i][j];
                    unsigned short hv = f2bf(x);
                    hu.u[i] = hv;
                    lu.u[i] = f2bf(x - bf2f(hv));
                }
                int idx = (d0 + j) * LDK + s0;
                *(bf16x4*)&Vthi[idx] = hu.v4;
                *(bf16x4*)&Vtlo[idx] = lu.v4;
            }
        }
        __syncthreads();

        const bool active = (sb * SBLK <= qmin + 63);   // else quadrant fully masked
        if (active) {
            // ---- QK^T ----
            f32x4 sacc[4][2];
#pragma unroll
            for (int m = 0; m < 4; ++m)
#pragma unroll
                for (int n = 0; n < 2; ++n) sacc[m][n] = (f32x4){0.f, 0.f, 0.f, 0.f};

#pragma unroll
            for (int kk = 0; kk < 2; ++kk) {
                bf16x8 kbh[2], kbl[2];
#pragma unroll
                for (int n = 0; n < 2; ++n) {
                    int s = wc * 32 + n * 16 + lr;
                    int idx = s * LDK + kk * 32 + lg * 8;
                    kbh[n] = *(const bf16x8*)&Khi[idx];
                    kbl[n] = *(const bf16x8*)&Klo[idx];
                }
#pragma unroll
                for (int m = 0; m < 4; ++m)
#pragma unroll
                    for (int n = 0; n < 2; ++n) {
                        sacc[m][n] = __builtin_amdgcn_mfma_f32_16x16x32_bf16(qh[m][kk], kbh[n], sacc[m][n], 0, 0, 0);
                        sacc[m][n] = __builtin_amdgcn_mfma_f32_16x16x32_bf16(qh[m][kk], kbl[n], sacc[m][n], 0, 0, 0);
                        sacc[m][n] = __builtin_amdgcn_mfma_f32_16x16x32_bf16(ql[m][kk], kbh[n], sacc[m][n], 0, 0, 0);
                    }
            }

            // ---- mask + convert + write S to LDS ----
            const bool needmask = (sb * SBLK + 63 > qmin);
#pragma unroll
            for (int m = 0; m < 4; ++m)
#pragma unroll
                for (int n = 0; n < 2; ++n) {
                    int sl = wc * 32 + n * 16 + lr;
                    int sg = sb * SBLK + sl;
#pragma unroll
                    for (int j = 0; j < 4; ++j) {
                        int rl = wm * 64 + m * 16 + lg * 4 + j;
                        int rg = qb * QBLK + rl;
                        float val = sacc[m][n][j];
                        if (needmask && sg > rg) val = 0.f;
                        unsigned short hv = f2bf(val);
                        int idx = rl * LDK + sl;
                        Shi[idx] = hv;
                        Slo[idx] = f2bf(val - bf2f(hv));
                    }
                }
        }
        __syncthreads();
        if (active) {
            // ---- PV: O += S @ V ----
#pragma unroll
            for (int kk = 0; kk < 2; ++kk) {
                bf16x8 vbh[2], vbl[2], sah[4], sal[4];
#pragma unroll
                for (int n = 0; n < 2; ++n) {
                    int d = wc * 32 + n * 16 + lr;
                    int idx = d * LDK + kk * 32 + lg * 8;
                    vbh[n] = *(const bf16x8*)&Vthi[idx];
                    vbl[n] = *(const bf16x8*)&Vtlo[idx];
                }
#pragma unroll
                for (int m = 0; m < 4; ++m) {
                    int r = wm * 64 + m * 16 + lr;
                    int idx = r * LDK + kk * 32 + lg * 8;
                    sah[m] = *(const bf16x8*)&Shi[idx];
                    sal[m] = *(const bf16x8*)&Slo[idx];
                }
#pragma unroll
                for (int m = 0; m < 4; ++m)
#pragma unroll
                    for (int n = 0; n < 2; ++n) {
                        oacc[m][n] = __builtin_amdgcn_mfma_f32_16x16x32_bf16(sah[m], vbh[n], oacc[m][n], 0, 0, 0);
                        oacc[m][n] = __builtin_amdgcn_mfma_f32_16x16x32_bf16(sah[m], vbl[n], oacc[m][n], 0, 0, 0);
                        oacc[m][n] = __builtin_amdgcn_mfma_f32_16x16x32_bf16(sal[m], vbh[n], oacc[m][n], 0, 0, 0);
                    }
            }
        }
    }

    // ---- epilogue: out[b][t][h*64 + d] ----
#pragma unroll
    for (int m = 0; m < 4; ++m)
#pragma unroll
        for (int n = 0; n < 2; ++n) {
            int dcol = wc * 32 + n * 16 + lr;
#pragma unroll
            for (int j = 0; j < 4; ++j) {
                int t = qb * QBLK + wm * 64 + m * 16 + lg * 4 + j;
                out[((size_t)b * T + t) * D + h * DH + dcol] = oacc[m][n][j];
            }
        }
}

// ---------------- launch ----------------
extern "C" void kernel_launch(void* const* d_in, const int* in_sizes, int n_in,
                              void* d_out, int out_size, void* d_ws, size_t ws_size,
                              hipStream_t stream) {
    const float* x    = (const float*)d_in[0];
    const float* Wq   = (const float*)d_in[1];
    const float* bq   = (const float*)d_in[2];
    float* out = (float*)d_out;
    float* ws  = (float*)d_ws;

    float* qr   = ws;
    float* kr   = ws + (size_t)QKV_ELEMS;
    float* vr   = ws + (size_t)2 * QKV_ELEMS;
    float* cosT = ws + (size_t)3 * QKV_ELEMS;
    float* sinT = cosT + T * 32;

    rope_tables_kernel<<<dim3((T * 32 + 255) / 256), dim3(256), 0, stream>>>(cosT, sinT);
    qkv_mfma_kernel<<<dim3(M / BMq, N3 / BNq), dim3(256), 0, stream>>>(
        x, Wq, bq, cosT, sinT, qr, kr, vr);
    retention_mfma_kernel<<<dim3(T / QBLK, B * H), dim3(256), 0, stream>>>(qr, kr, vr, out);
}

// Round 6
// 338.053 us; speedup vs baseline: 2.7692x; 1.1064x over previous
//
#include <hip/hip_runtime.h>

// Problem constants
#define B 8
#define T 768
#define D 1024
#define H 16
#define DH 64
#define M (B*T)      // 6144
#define N3 (3*D)     // 3072
#define KDIM D       // 1024
#define QKV_ELEMS (B*H*T*DH)  // 6291456 floats per tensor
#define XE ((size_t)M * KDIM)    // 6291456
#define WE ((size_t)N3 * KDIM)   // 3145728

typedef __attribute__((ext_vector_type(8))) short bf16x8;
typedef __attribute__((ext_vector_type(4))) short bf16x4;
typedef __attribute__((ext_vector_type(4))) float f32x4;

__device__ __forceinline__ unsigned short f2bf(float x) {
    union { float f; unsigned u; } a; a.f = x;
    unsigned r = a.u + 0x7FFFu + ((a.u >> 16) & 1u);
    return (unsigned short)(r >> 16);
}
__device__ __forceinline__ float bf2f(unsigned short h) {
    union { unsigned u; float f; } a; a.u = ((unsigned)h) << 16;
    return a.f;
}

// async global->LDS, 16B per lane; LDS dest must be wave-uniform base (HW adds lane*16)
__device__ __forceinline__ void gload_lds16(const void* g, void* l) {
    __builtin_amdgcn_global_load_lds(
        (const __attribute__((address_space(1))) void*)g,
        (__attribute__((address_space(3))) void*)l, 16, 0, 0);
}

// ---------------- Kernel 1: RoPE tables ----------------
__global__ void rope_tables_kernel(float* __restrict__ cosT, float* __restrict__ sinT) {
    int idx = blockIdx.x * blockDim.x + threadIdx.x;  // t*32 + i
    if (idx >= T * 32) return;
    int t = idx >> 5;
    int i = idx & 31;
    float inv_freq = powf(10000.0f, -(float)(2 * i) / 64.0f);
    float ang = (float)t * inv_freq;
    cosT[idx] = cosf(ang);
    sinT[idx] = sinf(ang);
}

// ---------------- Kernel 1b: fp32 -> bf16 hi/lo split (offline, once) ----------------
__global__ __launch_bounds__(256) void split_convert_kernel(
    const float* __restrict__ src, unsigned short* __restrict__ hi,
    unsigned short* __restrict__ lo, int n8)
{
    int i = blockIdx.x * blockDim.x + threadIdx.x;
    if (i >= n8) return;
    const float* p = src + (size_t)i * 8;
    float v[8];
    *(float4*)&v[0] = ((const float4*)p)[0];
    *(float4*)&v[4] = ((const float4*)p)[1];
    union { unsigned short u[8]; uint4 q; } hu, lu;
#pragma unroll
    for (int e = 0; e < 8; ++e) {
        unsigned short h = f2bf(v[e]);
        hu.u[e] = h;
        lu.u[e] = f2bf(v[e] - bf2f(h));
    }
    ((uint4*)hi)[i] = hu.q;
    ((uint4*)lo)[i] = lu.q;
}

#define BMq 128
#define BNq 128
#define BKq 32

// ---------------- Kernel 2 (fast): QKV GEMM, pre-split operands + global_load_lds ----------------
// LDS tiles [row][32k] bf16 linear, global source pre-swizzled q ^= (row>>2)&3 so the
// matching swizzled ds_read_b128 fragment reads are 2-way (free).
__global__ __launch_bounds__(256) void qkv_mfma2_kernel(
    const unsigned short* __restrict__ Xhi, const unsigned short* __restrict__ Xlo,
    const unsigned short* __restrict__ Whi, const unsigned short* __restrict__ Wlo,
    const float* __restrict__ bias, const float* __restrict__ cosT,
    const float* __restrict__ sinT, float* __restrict__ qr,
    float* __restrict__ kr, float* __restrict__ vr)
{
    __shared__ unsigned short Ah[BMq * BKq], Al[BMq * BKq];
    __shared__ unsigned short Bh[BNq * BKq], Bl[BNq * BKq];

    const int tid  = threadIdx.x;
    const int lane = tid & 63;
    const int w    = tid >> 6;      // wave 0..3
    const int wr   = w >> 1;        // wave row 0..1
    const int wc   = w & 1;         // wave col 0..1
    const int lr   = lane & 15;
    const int kc   = lane >> 4;     // k-quarter 0..3

    const int m0 = blockIdx.x * BMq;
    const int n0 = blockIdx.y * BNq;

    f32x4 acc[4][4];
#pragma unroll
    for (int m = 0; m < 4; ++m)
#pragma unroll
        for (int n = 0; n < 4; ++n) acc[m][n] = (f32x4){0.f, 0.f, 0.f, 0.f};

    for (int k0 = 0; k0 < KDIM; k0 += BKq) {
        __syncthreads();
        // ---- stage 4 tiles of 8KB via global_load_lds (2 chunks/wave/array) ----
#pragma unroll
        for (int i = 0; i < 2; ++i) {
            int c   = w * 128 + i * 64 + lane;              // 16B-chunk index 0..511
            int row = c >> 2;
            int qq  = (c & 3) ^ ((row >> 2) & 3);           // pre-swizzled source quarter
            size_t goffA = (size_t)(m0 + row) * KDIM + k0 + qq * 8;
            size_t goffB = (size_t)(n0 + row) * KDIM + k0 + qq * 8;
            int lbase = (w * 128 + i * 64) * 8;             // wave-uniform LDS base (ushort idx)
            gload_lds16(Xhi + goffA, &Ah[lbase]);
            gload_lds16(Xlo + goffA, &Al[lbase]);
            gload_lds16(Whi + goffB, &Bh[lbase]);
            gload_lds16(Wlo + goffB, &Bl[lbase]);
        }
        __syncthreads();   // compiler drains vmcnt before barrier

        // ---- fragment loads (swizzled) ----
        bf16x8 ah[4], al[4], bh[4], bl[4];
#pragma unroll
        for (int m = 0; m < 4; ++m) {
            int r = wr * 64 + m * 16 + lr;
            int idx = r * 32 + (kc ^ ((r >> 2) & 3)) * 8;
            ah[m] = *(const bf16x8*)&Ah[idx];
            al[m] = *(const bf16x8*)&Al[idx];
        }
#pragma unroll
        for (int n = 0; n < 4; ++n) {
            int ccol = wc * 64 + n * 16 + lr;
            int idx = ccol * 32 + (kc ^ ((ccol >> 2) & 3)) * 8;
            bh[n] = *(const bf16x8*)&Bh[idx];
            bl[n] = *(const bf16x8*)&Bl[idx];
        }

        // ---- MFMA: hi*hi + hi*lo + lo*hi ----
#pragma unroll
        for (int m = 0; m < 4; ++m)
#pragma unroll
            for (int n = 0; n < 4; ++n) {
                acc[m][n] = __builtin_amdgcn_mfma_f32_16x16x32_bf16(ah[m], bh[n], acc[m][n], 0, 0, 0);
                acc[m][n] = __builtin_amdgcn_mfma_f32_16x16x32_bf16(ah[m], bl[n], acc[m][n], 0, 0, 0);
                acc[m][n] = __builtin_amdgcn_mfma_f32_16x16x32_bf16(al[m], bh[n], acc[m][n], 0, 0, 0);
            }
    }

    // ---- epilogue: bias + RoPE + scatter to (B,H,T,DH) [verified r3] ----
    const int section = n0 >> 10;                       // 0=q,1=k,2=v
    float* dst = (section == 0) ? qr : (section == 1) ? kr : vr;
    const int hcol = ((n0 & 1023) >> 6) + wc;           // head index

    float biasv[2][2];
#pragma unroll
    for (int np = 0; np < 2; ++np) {
        biasv[np][0] = bias[n0 + wc * 64 + np * 16 + lr];
        biasv[np][1] = bias[n0 + wc * 64 + np * 16 + lr + 32];
    }

#pragma unroll
    for (int m = 0; m < 4; ++m) {
#pragma unroll
        for (int j = 0; j < 4; ++j) {
            int grow = m0 + wr * 64 + m * 16 + (lane >> 4) * 4 + j;
            int bidx = grow / T;
            int t = grow - bidx * T;
            float* rowp = dst + (((size_t)bidx * H + hcol) * T + t) * DH;
#pragma unroll
            for (int np = 0; np < 2; ++np) {
                int d = np * 16 + lr;                   // 0..31
                float vlo = acc[m][np][j]     + biasv[np][0];
                float vhi = acc[m][np + 2][j] + biasv[np][1];
                if (section < 2) {
                    float c = cosT[t * 32 + d];
                    float s = sinT[t * 32 + d];
                    float nl = vlo * c - vhi * s;
                    float nh = vhi * c + vlo * s;
                    vlo = nl; vhi = nh;
                }
                rowp[d]      = vlo;
                rowp[d + 32] = vhi;
            }
        }
    }
}

// ---------------- Kernel 2 (fallback, r5-verified): in-loop split ----------------
__global__ __launch_bounds__(256) void qkv_mfma_kernel(
    const float* __restrict__ X, const float* __restrict__ W,
    const float* __restrict__ bias, const float* __restrict__ cosT,
    const float* __restrict__ sinT, float* __restrict__ qr,
    float* __restrict__ kr, float* __restrict__ vr)
{
    __shared__ unsigned short Ahi[BMq * BKq];
    __shared__ unsigned short Alo[BMq * BKq];
    __shared__ unsigned short Bhi[BNq * BKq];
    __shared__ unsigned short Blo[BNq * BKq];

    const int tid  = threadIdx.x;
    const int lane = tid & 63;
    const int w    = tid >> 6;
    const int wr   = w >> 1;
    const int wc   = w & 1;
    const int lr   = lane & 15;
    const int kc   = lane >> 4;

    const int m0 = blockIdx.x * BMq;
    const int n0 = blockIdx.y * BNq;

    const int srow = tid >> 1;
    const int kh   = tid & 1;

    f32x4 acc[4][4];
#pragma unroll
    for (int m = 0; m < 4; ++m)
#pragma unroll
        for (int n = 0; n < 4; ++n) acc[m][n] = (f32x4){0.f, 0.f, 0.f, 0.f};

    for (int k0 = 0; k0 < KDIM; k0 += BKq) {
        __syncthreads();
        {
            const float* src = X + (size_t)(m0 + srow) * KDIM + k0 + kh * 16;
            float v[16];
#pragma unroll
            for (int i = 0; i < 4; ++i) ((float4*)v)[i] = ((const float4*)src)[i];
#pragma unroll
            for (int c = 0; c < 2; ++c) {
                int chunk = kh * 2 + c;
                int sidx = srow * 32 + ((chunk ^ ((srow >> 1) & 3)) * 8);
                union { unsigned short u[8]; bf16x8 v8; } hiu, lou;
#pragma unroll
                for (int e = 0; e < 8; ++e) {
                    float x = v[c * 8 + e];
                    unsigned short h = f2bf(x);
                    hiu.u[e] = h;
                    lou.u[e] = f2bf(x - bf2f(h));
                }
                *(bf16x8*)&Ahi[sidx] = hiu.v8;
                *(bf16x8*)&Alo[sidx] = lou.v8;
            }
        }
        {
            const float* src = W + (size_t)(n0 + srow) * KDIM + k0 + kh * 16;
            float v[16];
#pragma unroll
            for (int i = 0; i < 4; ++i) ((float4*)v)[i] = ((const float4*)src)[i];
#pragma unroll
            for (int c = 0; c < 2; ++c) {
                int chunk = kh * 2 + c;
                int sidx = srow * 32 + ((chunk ^ ((srow >> 1) & 3)) * 8);
                union { unsigned short u[8]; bf16x8 v8; } hiu, lou;
#pragma unroll
                for (int e = 0; e < 8; ++e) {
                    float x = v[c * 8 + e];
                    unsigned short h = f2bf(x);
                    hiu.u[e] = h;
                    lou.u[e] = f2bf(x - bf2f(h));
                }
                *(bf16x8*)&Bhi[sidx] = hiu.v8;
                *(bf16x8*)&Blo[sidx] = lou.v8;
            }
        }
        __syncthreads();

        bf16x8 ah[4], al[4], bh[4], bl[4];
#pragma unroll
        for (int m = 0; m < 4; ++m) {
            int row = wr * 64 + m * 16 + lr;
            int idx = row * 32 + ((kc ^ ((row >> 1) & 3)) * 8);
            ah[m] = *(const bf16x8*)&Ahi[idx];
            al[m] = *(const bf16x8*)&Alo[idx];
        }
#pragma unroll
        for (int n = 0; n < 4; ++n) {
            int col = wc * 64 + n * 16 + lr;
            int idx = col * 32 + ((kc ^ ((col >> 1) & 3)) * 8);
            bh[n] = *(const bf16x8*)&Bhi[idx];
            bl[n] = *(const bf16x8*)&Blo[idx];
        }

#pragma unroll
        for (int m = 0; m < 4; ++m)
#pragma unroll
            for (int n = 0; n < 4; ++n) {
                acc[m][n] = __builtin_amdgcn_mfma_f32_16x16x32_bf16(ah[m], bh[n], acc[m][n], 0, 0, 0);
                acc[m][n] = __builtin_amdgcn_mfma_f32_16x16x32_bf16(ah[m], bl[n], acc[m][n], 0, 0, 0);
                acc[m][n] = __builtin_amdgcn_mfma_f32_16x16x32_bf16(al[m], bh[n], acc[m][n], 0, 0, 0);
            }
    }

    const int section = n0 >> 10;
    float* dst = (section == 0) ? qr : (section == 1) ? kr : vr;
    const int hcol = ((n0 & 1023) >> 6) + wc;

    float biasv[2][2];
#pragma unroll
    for (int np = 0; np < 2; ++np) {
        biasv[np][0] = bias[n0 + wc * 64 + np * 16 + lr];
        biasv[np][1] = bias[n0 + wc * 64 + np * 16 + lr + 32];
    }

#pragma unroll
    for (int m = 0; m < 4; ++m) {
#pragma unroll
        for (int j = 0; j < 4; ++j) {
            int grow = m0 + wr * 64 + m * 16 + (lane >> 4) * 4 + j;
            int bidx = grow / T;
            int t = grow - bidx * T;
            float* rowp = dst + (((size_t)bidx * H + hcol) * T + t) * DH;
#pragma unroll
            for (int np = 0; np < 2; ++np) {
                int d = np * 16 + lr;
                float vlo = acc[m][np][j]     + biasv[np][0];
                float vhi = acc[m][np + 2][j] + biasv[np][1];
                if (section < 2) {
                    float c = cosT[t * 32 + d];
                    float s = sinT[t * 32 + d];
                    float nl = vlo * c - vhi * s;
                    float nh = vhi * c + vlo * s;
                    vlo = nl; vhi = nh;
                }
                rowp[d]      = vlo;
                rowp[d + 32] = vhi;
            }
        }
    }
}

// ---------------- Kernel 3: retention via bf16 split-3 MFMA (verified r5) ----------------
#define SBLK 64
#define QBLK 128
#define LDK 72

__global__ __launch_bounds__(256) void retention_mfma_kernel(
    const float* __restrict__ qr, const float* __restrict__ kr,
    const float* __restrict__ vr, float* __restrict__ out)
{
    __shared__ unsigned short Khi[SBLK * LDK], Klo[SBLK * LDK];   // [s][d]
    __shared__ unsigned short Vthi[DH * LDK], Vtlo[DH * LDK];     // [d][s] (transposed)
    __shared__ unsigned short Shi[QBLK * LDK], Slo[QBLK * LDK];   // [r][s]

    const int qb = blockIdx.x;       // 0..5
    const int bh = blockIdx.y;       // 0..127
    const int b = bh >> 4, h = bh & 15;
    const int tid = threadIdx.x;
    const int lane = tid & 63;
    const int w = tid >> 6;
    const int wm = w >> 1;           // q-half 0..1
    const int wc = w & 1;            // col-half 0..1
    const int lr = lane & 15;
    const int lg = lane >> 4;        // 0..3

    bf16x8 qh[4][2], ql[4][2];
    {
        const float* qp = qr + ((size_t)bh * T + (size_t)qb * QBLK + wm * 64) * DH;
#pragma unroll
        for (int m = 0; m < 4; ++m)
#pragma unroll
            for (int kk = 0; kk < 2; ++kk) {
                const float* p = qp + (m * 16 + lr) * DH + kk * 32 + lg * 8;
                float v[8];
                *(float4*)&v[0] = *(const float4*)p;
                *(float4*)&v[4] = *(const float4*)(p + 4);
                union { unsigned short u[8]; bf16x8 v8; } hu, lu;
#pragma unroll
                for (int e = 0; e < 8; ++e) {
                    unsigned short hv = f2bf(v[e]);
                    hu.u[e] = hv;
                    lu.u[e] = f2bf(v[e] - bf2f(hv));
                }
                qh[m][kk] = hu.v8;
                ql[m][kk] = lu.v8;
            }
    }

    f32x4 oacc[4][2];
#pragma unroll
    for (int m = 0; m < 4; ++m)
#pragma unroll
        for (int n = 0; n < 2; ++n) oacc[m][n] = (f32x4){0.f, 0.f, 0.f, 0.f};

    const int qmin = qb * QBLK + wm * 64;
    const int niter = 2 * qb + 2;

    for (int sb = 0; sb < niter; ++sb) {
        __syncthreads();
        {
            int row = tid >> 2, d0 = (tid & 3) * 16;
            const float* src = kr + ((size_t)bh * T + (size_t)sb * SBLK + row) * DH + d0;
            float v[16];
#pragma unroll
            for (int i = 0; i < 4; ++i) *(float4*)&v[i * 4] = *(const float4*)(src + i * 4);
#pragma unroll
            for (int c = 0; c < 2; ++c) {
                union { unsigned short u[8]; bf16x8 v8; } hu, lu;
#pragma unroll
                for (int e = 0; e < 8; ++e) {
                    float x = v[c * 8 + e];
                    unsigned short hv = f2bf(x);
                    hu.u[e] = hv;
                    lu.u[e] = f2bf(x - bf2f(hv));
                }
                int idx = row * LDK + d0 + c * 8;
                *(bf16x8*)&Khi[idx] = hu.v8;
                *(bf16x8*)&Klo[idx] = lu.v8;
            }
        }
        {
            int s0 = (tid >> 4) * 4, d0 = (tid & 15) * 4;
            const float* src = vr + ((size_t)bh * T + (size_t)sb * SBLK + s0) * DH + d0;
            float rv[4][4];
#pragma unroll
            for (int i = 0; i < 4; ++i) *(float4*)&rv[i][0] = *(const float4*)(src + (size_t)i * DH);
#pragma unroll
            for (int j = 0; j < 4; ++j) {
                union { unsigned short u[4]; bf16x4 v4; } hu, lu;
#pragma unroll
                for (int i = 0; i < 4; ++i) {
                    float x = rv[i][j];
                    unsigned short hv = f2bf(x);
                    hu.u[i] = hv;
                    lu.u[i] = f2bf(x - bf2f(hv));
                }
                int idx = (d0 + j) * LDK + s0;
                *(bf16x4*)&Vthi[idx] = hu.v4;
                *(bf16x4*)&Vtlo[idx] = lu.v4;
            }
        }
        __syncthreads();

        const bool active = (sb * SBLK <= qmin + 63);
        if (active) {
            f32x4 sacc[4][2];
#pragma unroll
            for (int m = 0; m < 4; ++m)
#pragma unroll
                for (int n = 0; n < 2; ++n) sacc[m][n] = (f32x4){0.f, 0.f, 0.f, 0.f};

#pragma unroll
            for (int kk = 0; kk < 2; ++kk) {
                bf16x8 kbh[2], kbl[2];
#pragma unroll
                for (int n = 0; n < 2; ++n) {
                    int s = wc * 32 + n * 16 + lr;
                    int idx = s * LDK + kk * 32 + lg * 8;
                    kbh[n] = *(const bf16x8*)&Khi[idx];
                    kbl[n] = *(const bf16x8*)&Klo[idx];
                }
#pragma unroll
                for (int m = 0; m < 4; ++m)
#pragma unroll
                    for (int n = 0; n < 2; ++n) {
                        sacc[m][n] = __builtin_amdgcn_mfma_f32_16x16x32_bf16(qh[m][kk], kbh[n], sacc[m][n], 0, 0, 0);
                        sacc[m][n] = __builtin_amdgcn_mfma_f32_16x16x32_bf16(qh[m][kk], kbl[n], sacc[m][n], 0, 0, 0);
                        sacc[m][n] = __builtin_amdgcn_mfma_f32_16x16x32_bf16(ql[m][kk], kbh[n], sacc[m][n], 0, 0, 0);
                    }
            }

            const bool needmask = (sb * SBLK + 63 > qmin);
#pragma unroll
            for (int m = 0; m < 4; ++m)
#pragma unroll
                for (int n = 0; n < 2; ++n) {
                    int sl = wc * 32 + n * 16 + lr;
                    int sg = sb * SBLK + sl;
#pragma unroll
                    for (int j = 0; j < 4; ++j) {
                        int rl = wm * 64 + m * 16 + lg * 4 + j;
                        int rg = qb * QBLK + rl;
                        float val = sacc[m][n][j];
                        if (needmask && sg > rg) val = 0.f;
                        unsigned short hv = f2bf(val);
                        int idx = rl * LDK + sl;
                        Shi[idx] = hv;
                        Slo[idx] = f2bf(val - bf2f(hv));
                    }
                }
        }
        __syncthreads();
        if (active) {
#pragma unroll
            for (int kk = 0; kk < 2; ++kk) {
                bf16x8 vbh[2], vbl[2], sah[4], sal[4];
#pragma unroll
                for (int n = 0; n < 2; ++n) {
                    int d = wc * 32 + n * 16 + lr;
                    int idx = d * LDK + kk * 32 + lg * 8;
                    vbh[n] = *(const bf16x8*)&Vthi[idx];
                    vbl[n] = *(const bf16x8*)&Vtlo[idx];
                }
#pragma unroll
                for (int m = 0; m < 4; ++m) {
                    int r = wm * 64 + m * 16 + lr;
                    int idx = r * LDK + kk * 32 + lg * 8;
                    sah[m] = *(const bf16x8*)&Shi[idx];
                    sal[m] = *(const bf16x8*)&Slo[idx];
                }
#pragma unroll
                for (int m = 0; m < 4; ++m)
#pragma unroll
                    for (int n = 0; n < 2; ++n) {
                        oacc[m][n] = __builtin_amdgcn_mfma_f32_16x16x32_bf16(sah[m], vbh[n], oacc[m][n], 0, 0, 0);
                        oacc[m][n] = __builtin_amdgcn_mfma_f32_16x16x32_bf16(sah[m], vbl[n], oacc[m][n], 0, 0, 0);
                        oacc[m][n] = __builtin_amdgcn_mfma_f32_16x16x32_bf16(sal[m], vbh[n], oacc[m][n], 0, 0, 0);
                    }
            }
        }
    }

#pragma unroll
    for (int m = 0; m < 4; ++m)
#pragma unroll
        for (int n = 0; n < 2; ++n) {
            int dcol = wc * 32 + n * 16 + lr;
#pragma unroll
            for (int j = 0; j < 4; ++j) {
                int t = qb * QBLK + wm * 64 + m * 16 + lg * 4 + j;
                out[((size_t)b * T + t) * D + h * DH + dcol] = oacc[m][n][j];
            }
        }
}

// ---------------- launch ----------------
extern "C" void kernel_launch(void* const* d_in, const int* in_sizes, int n_in,
                              void* d_out, int out_size, void* d_ws, size_t ws_size,
                              hipStream_t stream) {
    const float* x    = (const float*)d_in[0];
    const float* Wq   = (const float*)d_in[1];
    const float* bq   = (const float*)d_in[2];
    float* out = (float*)d_out;
    float* ws  = (float*)d_ws;

    float* qr   = ws;
    float* kr   = ws + (size_t)QKV_ELEMS;
    float* vr   = ws + (size_t)2 * QKV_ELEMS;
    float* cosT = ws + (size_t)3 * QKV_ELEMS;
    float* sinT = cosT + T * 32;

    const size_t float_bytes = ((size_t)3 * QKV_ELEMS + 2 * T * 32) * sizeof(float);
    unsigned short* Xhi = (unsigned short*)((char*)d_ws + float_bytes);
    unsigned short* Xlo = Xhi + XE;
    unsigned short* Whi = Xlo + XE;
    unsigned short* Wlo = Whi + WE;
    const size_t need = float_bytes + (2 * XE + 2 * WE) * sizeof(unsigned short);

    rope_tables_kernel<<<dim3((T * 32 + 255) / 256), dim3(256), 0, stream>>>(cosT, sinT);

    if (ws_size >= need) {
        split_convert_kernel<<<dim3((int)(XE / 8 / 256)), dim3(256), 0, stream>>>(x,  Xhi, Xlo, (int)(XE / 8));
        split_convert_kernel<<<dim3((int)(WE / 8 / 256)), dim3(256), 0, stream>>>(Wq, Whi, Wlo, (int)(WE / 8));
        qkv_mfma2_kernel<<<dim3(M / BMq, N3 / BNq), dim3(256), 0, stream>>>(
            Xhi, Xlo, Whi, Wlo, bq, cosT, sinT, qr, kr, vr);
    } else {
        qkv_mfma_kernel<<<dim3(M / BMq, N3 / BNq), dim3(256), 0, stream>>>(
            x, Wq, bq, cosT, sinT, qr, kr, vr);
    }

    retention_mfma_kernel<<<dim3(T / QBLK, B * H), dim3(256), 0, stream>>>(qr, kr, vr, out);
}